// Round 2
// baseline (234.808 us; speedup 1.0000x reference)
//
#include <hip/hip_runtime.h>

#define ROW_LEN 2048
#define BLOCK   256
#define ROWS_PER_WAVE 4
#define EPS     1e-5f

typedef float floatx4 __attribute__((ext_vector_type(4)));

__global__ __launch_bounds__(BLOCK, 4) void RMSNorm_56607668961691_kernel(
    const float* __restrict__ x,
    const float* __restrict__ g,
    float* __restrict__ out)
{
    const int wave = threadIdx.x >> 6;
    const int lane = threadIdx.x & 63;
    const size_t wid  = (size_t)blockIdx.x * (BLOCK / 64) + wave;
    const size_t row0 = wid * ROWS_PER_WAVE;

    const float4* __restrict__ xr   = reinterpret_cast<const float4*>(x + row0 * ROW_LEN) + lane;
    float4* __restrict__       outr = reinterpret_cast<float4*>(out + row0 * ROW_LEN) + lane;
    const float4* __restrict__ gv   = reinterpret_cast<const float4*>(g) + lane;

    // g (8 KiB) resident in registers for all 4 rows: 8 float4/lane.
    float4 gr[8];
    #pragma unroll
    for (int j = 0; j < 8; ++j) gr[j] = gv[j * 64];

    // Prologue: row 0 loads in flight.
    float4 cur[8];
    #pragma unroll
    for (int j = 0; j < 8; ++j) cur[j] = xr[j * 64];

    #pragma unroll
    for (int r = 0; r < ROWS_PER_WAVE; ++r) {
        // Software pipeline: issue ALL of row r+1's loads BEFORE touching row r's
        // values. Compiler then waits with vmcnt(8), not vmcnt(0) — next-row
        // loads stay outstanding across the reduce.
        float4 nxt[8];
        if (r + 1 < ROWS_PER_WAVE) {
            const float4* xn = xr + (size_t)(r + 1) * (ROW_LEN / 4);
            #pragma unroll
            for (int j = 0; j < 8; ++j) nxt[j] = xn[j * 64];
        }

        // 4 independent accumulator chains.
        float s0 = 0.f, s1 = 0.f, s2 = 0.f, s3 = 0.f;
        #pragma unroll
        for (int j = 0; j < 8; ++j) {
            s0 += cur[j].x * cur[j].x;
            s1 += cur[j].y * cur[j].y;
            s2 += cur[j].z * cur[j].z;
            s3 += cur[j].w * cur[j].w;
        }
        float ss = (s0 + s1) + (s2 + s3);

        // 64-lane butterfly; every lane ends with the row total.
        #pragma unroll
        for (int off = 32; off > 0; off >>= 1)
            ss += __shfl_xor(ss, off, 64);

        const float scale = rsqrtf(ss * (1.0f / (float)ROW_LEN) + EPS);

        // Non-temporal stores: out is never re-read; don't evict x from LLC.
        float4* o = outr + (size_t)r * (ROW_LEN / 4);
        #pragma unroll
        for (int j = 0; j < 8; ++j) {
            float4 ov;
            ov.x = cur[j].x * scale * gr[j].x;
            ov.y = cur[j].y * scale * gr[j].y;
            ov.z = cur[j].z * scale * gr[j].z;
            ov.w = cur[j].w * scale * gr[j].w;
            __builtin_nontemporal_store(*reinterpret_cast<floatx4*>(&ov),
                                        reinterpret_cast<floatx4*>(&o[j * 64]));
        }

        if (r + 1 < ROWS_PER_WAVE) {
            #pragma unroll
            for (int j = 0; j < 8; ++j) cur[j] = nxt[j];
        }
    }
}

extern "C" void kernel_launch(void* const* d_in, const int* in_sizes, int n_in,
                              void* d_out, int out_size, void* d_ws, size_t ws_size,
                              hipStream_t stream) {
    const float* x = (const float*)d_in[0];
    const float* g = (const float*)d_in[1];
    float* out = (float*)d_out;

    const int rows = in_sizes[0] / ROW_LEN;                    // 16384
    const int grid = rows / (ROWS_PER_WAVE * (BLOCK / 64));    // 1024 blocks, 4/CU
    RMSNorm_56607668961691_kernel<<<grid, BLOCK, 0, stream>>>(x, g, out);
}